// Round 6
// baseline (512.839 us; speedup 1.0000x reference)
//
#include <hip/hip_runtime.h>
#include <hip/hip_bf16.h>

typedef __hip_bfloat16 bf16;

#define D 64        // LATENT
#define BSH 8       // 256 nodes per bucket
#define CAP 5120    // bucket capacity (mean 4096, sigma ~64 -> 16 sigma margin)
#define EPB 16384   // edges per k_part block (LDS-staged)
#define PTB 1024    // k_part / k_scatter threads per block
#define NPW 8       // nodes per wave in k_emb0 (amortizes W-register loads)
#define GNP 8       // nodes per wave in prop kernels (equal-degree groups)
#define DBINS 64    // degree bins
#define DCAP 16384  // per-bin region capacity (peak bin ~15K at Poisson(16), 9+ sigma)

// ---------------- init cursors ----------------

__global__ __launch_bounds__(256) void k_initcur(int* __restrict__ gcur, int nbk,
                                                 int* __restrict__ dgcur) {
    int i = blockIdx.x * 256 + threadIdx.x;
    if (i < nbk) gcur[i] = i * CAP;
    if (i < DBINS) dgcur[i] = i * DCAP;
}

// ---------------- pass 1: partition edges into target buckets ----------------
// record = (frm << 8) | (to & 255); bucket = to >> 8, fixed CAP region per bucket.
// LDS-staged counting sort: random scatter goes to LDS; global writes are
// coalesced per-bucket runs.

__global__ __launch_bounds__(1024) void k_part(const int* __restrict__ frm,
                                               const int* __restrict__ to,
                                               int* __restrict__ gcur,
                                               int* __restrict__ be, int E, int nbk) {
    __shared__ int hist[1024];    // bucket count, then running LDS cursor
    __shared__ int lofs[1024];    // exclusive scan (static)
    __shared__ int gbase[1024];   // reserved global base per bucket
    __shared__ int wsum[16];
    __shared__ int stage[EPB];    // staged records (64 KB)

    int tid = threadIdx.x;
    hist[tid] = 0;
    __syncthreads();

    int base = blockIdx.x * EPB;
    int  f[16], bk[16], tl[16];
    bool va[16];
    #pragma unroll
    for (int k = 0; k < 16; k++) {
        int i = base + k * PTB + tid;
        va[k] = (i < E);
        int ic = va[k] ? i : base;
        int t = to[ic];
        f[k]  = frm[ic];
        bk[k] = t >> BSH;
        tl[k] = t & 255;
        if (va[k]) atomicAdd(&hist[bk[k]], 1);
    }
    __syncthreads();

    // exclusive scan of hist (wave shfl scan + wave-sum scan)
    int c = hist[tid];
    int lane = tid & 63, wv = tid >> 6;
    int x = c;
    #pragma unroll
    for (int off = 1; off < 64; off <<= 1) {
        int y = __shfl_up(x, off);
        if (lane >= off) x += y;
    }
    if (lane == 63) wsum[wv] = x;
    __syncthreads();
    if (wv == 0) {
        int wval = (lane < 16) ? wsum[lane] : 0;
        #pragma unroll
        for (int off = 1; off < 16; off <<= 1) {
            int y = __shfl_up(wval, off);
            if (lane >= off) wval += y;
        }
        if (lane < 16) wsum[lane] = wval;
    }
    __syncthreads();
    int excl = x + (wv ? wsum[wv - 1] : 0) - c;
    lofs[tid]  = excl;
    gbase[tid] = (c > 0 && tid < nbk) ? atomicAdd(&gcur[tid], c) : 0;
    hist[tid]  = excl;            // running cursor
    __syncthreads();

    // scatter records into LDS staging
    #pragma unroll
    for (int k = 0; k < 16; k++) {
        if (va[k]) {
            int p = atomicAdd(&hist[bk[k]], 1);
            stage[p] = (f[k] << 8) | tl[k];
        }
    }
    __syncthreads();

    // coalesced flush: wave per bucket (strided); lane-contiguous stores
    for (int b = wv; b < nbk; b += 16) {
        int ls = lofs[b];
        int le = hist[b];         // cursor == end of run
        int gd = gbase[b];
        for (int i = ls + lane; i < le; i += 64)
            be[gd + (i - ls)] = stage[i];
    }
}

// ---------------- scan bucket counts -> bstart; single block ----------------

__global__ void k_bscan(const int* __restrict__ gcur, int* __restrict__ bstart,
                        int* __restrict__ row_start, int nbk, int N, int E) {
    __shared__ int s[1024];
    int t = threadIdx.x;
    int x = (t < nbk) ? (gcur[t] - t * CAP) : 0;   // bucket count
    s[t] = x;
    __syncthreads();
    #pragma unroll
    for (int off = 1; off < 1024; off <<= 1) {
        int v = s[t] + ((t >= off) ? s[t - off] : 0);
        __syncthreads();
        s[t] = v;
        __syncthreads();
    }
    if (t < nbk) bstart[t] = s[t] - x;             // exclusive
    if (t == 0) row_start[N] = E;
}

// ---------------- pass 2: per-bucket hist + scan + scatter + degree-binning ------
// Computes deg/dis/row_start for the bucket's 256 nodes, scatters into CSR, and
// bins nodes by degree into dperm (fixed DCAP region per bin) for the prop
// kernels' equal-degree wave groups.

__global__ __launch_bounds__(1024) void k_scatter(const int* __restrict__ gcur,
                                                  const int* __restrict__ bstart,
                                                  const int* __restrict__ be,
                                                  int* __restrict__ row_start,
                                                  float* __restrict__ dis,
                                                  int* __restrict__ csr,
                                                  int* __restrict__ dgcur,
                                                  int* __restrict__ dperm, int N) {
    __shared__ int hist[256];
    __shared__ int scn[256];
    __shared__ int dh[DBINS];
    __shared__ int dbl[DBINS];
    int b = blockIdx.x;
    int t = threadIdx.x;
    if (t < 256) hist[t] = 0;
    if (t >= 256 && t < 256 + DBINS) dh[t - 256] = 0;
    __syncthreads();

    int base = b * CAP;
    int cnt  = gcur[b] - base;
    for (int i = t; i < cnt; i += PTB)
        atomicAdd(&hist[be[base + i] & 255], 1);
    __syncthreads();

    int d = 0;
    if (t < 256) { d = hist[t]; scn[t] = d; }
    __syncthreads();
    #pragma unroll
    for (int off = 1; off < 256; off <<= 1) {
        int v = 0;
        if (t < 256) v = scn[t] + ((t >= off) ? scn[t - off] : 0);
        __syncthreads();
        if (t < 256) scn[t] = v;
        __syncthreads();
    }
    int rs = 0, node = 0, bin = 0;
    bool vn = false;
    if (t < 256) {
        rs = bstart[b] + (scn[t] - d);
        node = (b << BSH) + t;
        vn = (node < N);
        if (vn) {
            row_start[node] = rs;
            dis[node] = (d > 0) ? rsqrtf((float)d) : 0.0f;
            bin = min(d, DBINS - 1);
            atomicAdd(&dh[bin], 1);
        }
    }
    __syncthreads();
    if (t < DBINS) {
        int c = dh[t];
        dbl[t] = (c > 0) ? atomicAdd(&dgcur[t], c) : 0;
        dh[t] = 0;                                  // becomes local cursor
    }
    __syncthreads();
    if (vn) {
        int lo = atomicAdd(&dh[bin], 1);
        dperm[dbl[bin] + lo] = node;
    }
    if (t < 256) hist[t] = rs;                      // becomes CSR cursor
    __syncthreads();

    for (int i = t; i < cnt; i += PTB) {
        int rec = be[base + i];
        int pos = atomicAdd(&hist[rec & 255], 1);
        csr[pos] = rec >> 8;
    }
}

// ---------------- compact degree-binned regions into dense perm[N] ----------------

__global__ __launch_bounds__(1024) void k_dcompact(const int* __restrict__ dgcur,
                                                   const int* __restrict__ dperm,
                                                   int* __restrict__ perm) {
    __shared__ int off[DBINS + 1];
    int t = threadIdx.x;
    if (t == 0) {
        int acc = 0;
        for (int b2 = 0; b2 < DBINS; b2++) {
            off[b2] = acc;
            acc += dgcur[b2] - b2 * DCAP;
        }
        off[DBINS] = acc;
    }
    __syncthreads();
    for (int b2 = 0; b2 < DBINS; b2++) {
        int o = off[b2], c = off[b2 + 1] - o;
        for (int i = t; i < c; i += 1024)
            perm[o + i] = dperm[b2 * DCAP + i];
    }
}

// ---------------- emb0 = embedding + feature projection ----------------
// One wave handles NPW nodes; lane = dim. W column hoisted into registers once
// per wave. Feature loads are float4 broadcasts.
// out0 = fp32 emb0; y0 = bf16(dis * emb0) gather table.

__global__ __launch_bounds__(256) void k_emb0(const float* __restrict__ emb,
                       const float* __restrict__ uf,    // [NU,16]
                       const float* __restrict__ bn,    // [NB,8]
                       const float* __restrict__ bg,    // [NB,32]
                       const float* __restrict__ Wu,    // [16,64]
                       const float* __restrict__ bu,    // [64]
                       const float* __restrict__ Wn,    // [8,64]
                       const float* __restrict__ bnb,   // [64]
                       const float* __restrict__ Wg,    // [32,64]
                       const float* __restrict__ bgb,   // [64]
                       const float* __restrict__ dis,
                       float* __restrict__ out0, bf16* __restrict__ y0,
                       int N, int NU, int ublocks) {
    int lane = threadIdx.x & 63;
    int wsub = __builtin_amdgcn_readfirstlane(threadIdx.x >> 6);  // wave-uniform

    if (blockIdx.x < ublocks) {
        // ---- user nodes ----
        float w[16];
        #pragma unroll
        for (int k = 0; k < 16; k++) w[k] = Wu[k * D + lane];
        float bias = bu[lane];

        int node0 = (blockIdx.x * 4 + wsub) * NPW;
        for (int n = 0; n < NPW; n++) {
            int node = node0 + n;
            if (node >= NU) break;
            const float4* f = (const float4*)(uf + (size_t)node * 16);
            float4 f0 = f[0], f1 = f[1], f2 = f[2], f3 = f[3];
            float p = bias
                + f0.x * w[0]  + f0.y * w[1]  + f0.z * w[2]  + f0.w * w[3]
                + f1.x * w[4]  + f1.y * w[5]  + f1.z * w[6]  + f1.w * w[7]
                + f2.x * w[8]  + f2.y * w[9]  + f2.z * w[10] + f2.w * w[11]
                + f3.x * w[12] + f3.y * w[13] + f3.z * w[14] + f3.w * w[15];
            size_t idx = (size_t)node * D + lane;
            float v = emb[idx] + p;
            out0[idx] = v;
            y0[idx]   = __float2bfloat16(dis[node] * v);
        }
    } else {
        // ---- book nodes ----
        float wn[8], wg[32];
        #pragma unroll
        for (int k = 0; k < 8; k++)  wn[k] = Wn[k * D + lane];
        #pragma unroll
        for (int k = 0; k < 32; k++) wg[k] = Wg[k * D + lane];
        float bias = bnb[lane] + bgb[lane];

        int b0 = ((blockIdx.x - ublocks) * 4 + wsub) * NPW;
        for (int n = 0; n < NPW; n++) {
            int b = b0 + n;
            int node = NU + b;
            if (node >= N) break;
            const float4* fn = (const float4*)(bn + (size_t)b * 8);
            float4 n0 = fn[0], n1 = fn[1];
            const float4* fg = (const float4*)(bg + (size_t)b * 32);
            float p = bias
                + n0.x * wn[0] + n0.y * wn[1] + n0.z * wn[2] + n0.w * wn[3]
                + n1.x * wn[4] + n1.y * wn[5] + n1.z * wn[6] + n1.w * wn[7];
            #pragma unroll
            for (int q = 0; q < 8; q++) {
                float4 g = fg[q];
                p += g.x * wg[4*q]   + g.y * wg[4*q+1]
                   + g.z * wg[4*q+2] + g.w * wg[4*q+3];
            }
            size_t idx = (size_t)node * D + lane;
            float v = emb[idx] + p;
            out0[idx] = v;
            y0[idx]   = __float2bfloat16(dis[node] * v);
        }
    }
}

// ---------------- bf16x2 helpers ----------------

static __device__ __forceinline__ unsigned int pack_bf16x2(float e, float o) {
    bf16 a = __float2bfloat16(e);
    bf16 b = __float2bfloat16(o);
    unsigned short ua = __builtin_bit_cast(unsigned short, a);
    unsigned short ub = __builtin_bit_cast(unsigned short, b);
    return (unsigned int)ua | ((unsigned int)ub << 16);
}

// ---------------- gather core: GNP equal-degree nodes per wave -------------------
// Round-4 interleaved structure (best measured: 2 edges per dword load, lanes
// 0-31 even edges / 32-63 odd edges, csr coop-load + shfl distribute), widened
// to GNP=8 nodes per wave. Nodes come from the degree-grouped perm, so all 8
// rows have near-equal length: lockstep masking waste ~1, and the chunk loop
// count is wave-uniform. 8 csr + 64 gather loads in flight per iteration.

static __device__ __forceinline__ void gatherN(
        const int* __restrict__ row_start, const int* __restrict__ csr,
        const unsigned int* __restrict__ y32, const int* __restrict__ perm,
        int n0, int N, int lane,
        int (&nd)[GNP], float (&a0)[GNP], float (&a1)[GNP]) {
    int half = lane >> 5;
    int lh   = lane & 31;
    int l16  = lane & 15;

    int sv[GNP], ev[GNP];
    #pragma unroll
    for (int g = 0; g < GNP; g++) {
        int slot = min(n0 + g, N - 1);
        int node = perm[slot];
        nd[g] = node;
        sv[g] = row_start[node];
        ev[g] = (n0 + g < N) ? row_start[node + 1] : sv[g];
        a0[g] = 0.f;
        a1[g] = 0.f;
    }

    for (int c = 0; ; c++) {
        int jv[GNP], base[GNP];
        #pragma unroll
        for (int g = 0; g < GNP; g++) {
            base[g] = sv[g] + 16 * c;
            jv[g] = csr[min(base[g] + l16, max(ev[g] - 1, 0))];
        }
        #pragma unroll
        for (int u = 0; u < 8; u++) {
            #pragma unroll
            for (int g = 0; g < GNP; g++) {
                int idx = 2 * u + half;
                int j = __shfl(jv[g], idx);
                unsigned int d = y32[((unsigned int)j << 5) + lh];
                d = (base[g] + idx < ev[g]) ? d : 0u;
                a0[g] += __uint_as_float(d << 16);
                a1[g] += __uint_as_float(d & 0xffff0000u);
            }
        }
        bool cont = false;
        #pragma unroll
        for (int g = 0; g < GNP; g++) cont = cont || (base[g] + 16 < ev[g]);
        if (!cont) break;
    }

    // combine even-edge and odd-edge streams across halves
    #pragma unroll
    for (int g = 0; g < GNP; g++) {
        a0[g] += __shfl_xor(a0[g], 32);
        a1[g] += __shfl_xor(a1[g], 32);
    }
}

// ---------------- propagation layer ----------------
// y_in is pre-scaled by dis[src]. x = dis[t]*sum; y_out = bf16(dis[t]*x).
// Lane lh holds dims {2lh, 2lh+1}; half 0 stores x_out, half 1 stores y_out.

__global__ __launch_bounds__(256) void k_prop(const int* __restrict__ row_start,
                       const int* __restrict__ csr,
                       const float* __restrict__ dis,
                       const bf16* __restrict__ y_in,
                       bf16* __restrict__ x_out,
                       bf16* __restrict__ y_out,
                       const int* __restrict__ perm, int N) {
    int lane = threadIdx.x & 63;
    int wid = __builtin_amdgcn_readfirstlane((int)(blockIdx.x * 4 + (threadIdx.x >> 6)));
    int n0 = wid * GNP;
    if (n0 >= N) return;

    int nd[GNP];
    float a0[GNP], a1[GNP];
    gatherN(row_start, csr, (const unsigned int*)y_in, perm, n0, N, lane, nd, a0, a1);

    int half = lane >> 5;
    int lh   = lane & 31;
    #pragma unroll
    for (int g = 0; g < GNP; g++) {
        if (n0 + g >= N) break;
        int node = nd[g];
        float dt = dis[node];
        float x0  = dt * a0[g];
        float x1v = dt * a1[g];
        unsigned int w = (unsigned int)node * 32 + lh;
        if (half == 0) {
            ((unsigned int*)x_out)[w] = pack_bf16x2(x0, x1v);
        } else {
            ((unsigned int*)y_out)[w] = pack_bf16x2(dt * x0, dt * x1v);
        }
    }
}

// ---------------- last layer fused with final mean: out1 = (e0 + x1 + x2 + x3)/4 ----

__global__ __launch_bounds__(256) void k_prop_last(const int* __restrict__ row_start,
                       const int* __restrict__ csr,
                       const float* __restrict__ dis,
                       const bf16* __restrict__ y_in,
                       const float* __restrict__ out0,
                       const bf16* __restrict__ x1,
                       const bf16* __restrict__ x2,
                       float* __restrict__ out1,
                       const int* __restrict__ perm, int N) {
    int lane = threadIdx.x & 63;
    int wid = __builtin_amdgcn_readfirstlane((int)(blockIdx.x * 4 + (threadIdx.x >> 6)));
    int n0 = wid * GNP;
    if (n0 >= N) return;

    int nd[GNP];
    float a0[GNP], a1[GNP];
    gatherN(row_start, csr, (const unsigned int*)y_in, perm, n0, N, lane, nd, a0, a1);

    int half = lane >> 5;
    int lh   = lane & 31;
    #pragma unroll
    for (int g = 0; g < GNP; g++) {
        if (n0 + g >= N) break;
        int node = nd[g];
        float dt = dis[node];
        float x3e = dt * a0[g];   // even dim of pair
        float x3o = dt * a1[g];   // odd dim of pair
        if (half == 0) {
            unsigned int w = (unsigned int)node * 32 + lh;
            float2 o0 = ((const float2*)out0)[w];
            unsigned int p1 = ((const unsigned int*)x1)[w];
            unsigned int p2 = ((const unsigned int*)x2)[w];
            float e1 = __uint_as_float(p1 << 16);
            float o1 = __uint_as_float(p1 & 0xffff0000u);
            float e2 = __uint_as_float(p2 << 16);
            float o2 = __uint_as_float(p2 & 0xffff0000u);
            float2 r;
            r.x = (o0.x + e1 + e2 + x3e) * 0.25f;
            r.y = (o0.y + o1 + o2 + x3o) * 0.25f;
            ((float2*)out1)[w] = r;
        }
    }
}

// ---------------- launch ----------------

extern "C" void kernel_launch(void* const* d_in, const int* in_sizes, int n_in,
                              void* d_out, int out_size, void* d_ws, size_t ws_size,
                              hipStream_t stream) {
    const int E  = in_sizes[0] / 2;
    const int N  = in_sizes[1] / D;
    const int NU = in_sizes[2] / 16;
    const int nbk = (N + 255) >> BSH;        // buckets of 256 nodes (<= 1024 required)

    const int*   frm = (const int*)d_in[0];
    const int*   to  = frm + E;
    const float* emb = (const float*)d_in[1];
    const float* uf  = (const float*)d_in[2];
    const float* bn  = (const float*)d_in[3];
    const float* bg  = (const float*)d_in[4];
    const float* Wu  = (const float*)d_in[5];
    const float* bu  = (const float*)d_in[6];
    const float* Wn  = (const float*)d_in[7];
    const float* bnb = (const float*)d_in[8];
    const float* Wg  = (const float*)d_in[9];
    const float* bgb = (const float*)d_in[10];

    // workspace layout
    char* p = (char*)d_ws;
    const size_t ND = (size_t)N * D;
    bf16*  y0        = (bf16*)p;   p += ND * sizeof(bf16);    // also reused as y2
    bf16*  y1        = (bf16*)p;   p += ND * sizeof(bf16);
    bf16*  x1        = (bf16*)p;   p += ND * sizeof(bf16);
    bf16*  x2        = (bf16*)p;   p += ND * sizeof(bf16);
    float* dis       = (float*)p;  p += (size_t)N * sizeof(float);
    int*   row_start = (int*)p;    p += ((size_t)N + 16) * sizeof(int);
    int*   bstart    = (int*)p;    p += 1024 * sizeof(int);
    int*   gcur      = (int*)p;    p += (size_t)nbk * sizeof(int);
    int*   dgcur     = (int*)p;    p += DBINS * sizeof(int);
    int*   perm      = (int*)p;    p += (size_t)N * sizeof(int);
    int*   csr       = (int*)p;    p += (size_t)E * sizeof(int);
    int*   be        = (int*)p;    p += (size_t)nbk * CAP * sizeof(int);
    int*   dperm     = (int*)p;    p += (size_t)DBINS * DCAP * sizeof(int);

    const int TB = 256;
    const int gridProp = (N + 4 * GNP - 1) / (4 * GNP);  // 8 nodes/wave, 4 waves/block
    const int gridPart = (E + EPB - 1) / EPB;

    k_initcur<<<(nbk + TB - 1) / TB, TB, 0, stream>>>(gcur, nbk, dgcur);
    k_part   <<<gridPart, PTB, 0, stream>>>(frm, to, gcur, be, E, nbk);
    k_bscan  <<<1, 1024, 0, stream>>>(gcur, bstart, row_start, nbk, N, E);
    k_scatter<<<nbk, PTB, 0, stream>>>(gcur, bstart, be, row_start, dis, csr,
                                       dgcur, dperm, N);
    k_dcompact<<<1, 1024, 0, stream>>>(dgcur, dperm, perm);

    float* out0 = (float*)d_out;       // emb0 output (fp32)
    float* out1 = out0 + ND;           // layer-mean output (fp32)

    // k_emb0: one wave per NPW nodes; user blocks then book blocks in one launch
    const int NB = N - NU;
    const int uwaves  = (NU + NPW - 1) / NPW;
    const int ublocks = (uwaves + 3) / 4;
    const int bwaves  = (NB + NPW - 1) / NPW;
    const int bblocks = (bwaves + 3) / 4;
    k_emb0<<<ublocks + bblocks, TB, 0, stream>>>(emb, uf, bn, bg, Wu, bu, Wn, bnb,
                                                 Wg, bgb, dis, out0, y0, N, NU, ublocks);

    k_prop     <<<gridProp, TB, 0, stream>>>(row_start, csr, dis, y0, x1, y1, perm, N);
    k_prop     <<<gridProp, TB, 0, stream>>>(row_start, csr, dis, y1, x2, y0, perm, N);  // y2 -> y0
    k_prop_last<<<gridProp, TB, 0, stream>>>(row_start, csr, dis, y0, out0, x1, x2,
                                             out1, perm, N);
}

// Round 8
// 390.064 us; speedup vs baseline: 1.3148x; 1.3148x over previous
//
#include <hip/hip_runtime.h>
#include <hip/hip_bf16.h>

typedef __hip_bfloat16 bf16;

#define D 64        // LATENT
#define BSH 8       // 256 nodes per bucket
#define CAP 5120    // bucket capacity (mean 4096, sigma ~64 -> 16 sigma margin)
#define EPB 16384   // edges per k_part block (LDS-staged)
#define PTB 1024    // k_part / k_scatter threads per block
#define NPW 8       // nodes per wave in k_emb0 (amortizes W-register loads)
#define GNP 6       // consecutive nodes per wave in prop kernels (MLP width)

// ---------------- init bucket cursors ----------------

__global__ __launch_bounds__(256) void k_initcur(int* __restrict__ gcur, int nbk) {
    int i = blockIdx.x * 256 + threadIdx.x;
    if (i < nbk) gcur[i] = i * CAP;
}

// ---------------- pass 1: partition edges into target buckets ----------------
// record = (frm << 8) | (to & 255); bucket = to >> 8, fixed CAP region per bucket.
// LDS-staged counting sort: random scatter goes to LDS; global writes are
// coalesced per-bucket runs.

__global__ __launch_bounds__(1024) void k_part(const int* __restrict__ frm,
                                               const int* __restrict__ to,
                                               int* __restrict__ gcur,
                                               int* __restrict__ be, int E, int nbk) {
    __shared__ int hist[1024];    // bucket count, then running LDS cursor
    __shared__ int lofs[1024];    // exclusive scan (static)
    __shared__ int gbase[1024];   // reserved global base per bucket
    __shared__ int wsum[16];
    __shared__ int stage[EPB];    // staged records (64 KB)

    int tid = threadIdx.x;
    hist[tid] = 0;
    __syncthreads();

    int base = blockIdx.x * EPB;
    int  f[16], bk[16], tl[16];
    bool va[16];
    #pragma unroll
    for (int k = 0; k < 16; k++) {
        int i = base + k * PTB + tid;
        va[k] = (i < E);
        int ic = va[k] ? i : base;
        int t = to[ic];
        f[k]  = frm[ic];
        bk[k] = t >> BSH;
        tl[k] = t & 255;
        if (va[k]) atomicAdd(&hist[bk[k]], 1);
    }
    __syncthreads();

    // exclusive scan of hist (wave shfl scan + wave-sum scan)
    int c = hist[tid];
    int lane = tid & 63, wv = tid >> 6;
    int x = c;
    #pragma unroll
    for (int off = 1; off < 64; off <<= 1) {
        int y = __shfl_up(x, off);
        if (lane >= off) x += y;
    }
    if (lane == 63) wsum[wv] = x;
    __syncthreads();
    if (wv == 0) {
        int wval = (lane < 16) ? wsum[lane] : 0;
        #pragma unroll
        for (int off = 1; off < 16; off <<= 1) {
            int y = __shfl_up(wval, off);
            if (lane >= off) wval += y;
        }
        if (lane < 16) wsum[lane] = wval;
    }
    __syncthreads();
    int excl = x + (wv ? wsum[wv - 1] : 0) - c;
    lofs[tid]  = excl;
    gbase[tid] = (c > 0 && tid < nbk) ? atomicAdd(&gcur[tid], c) : 0;
    hist[tid]  = excl;            // running cursor
    __syncthreads();

    // scatter records into LDS staging
    #pragma unroll
    for (int k = 0; k < 16; k++) {
        if (va[k]) {
            int p = atomicAdd(&hist[bk[k]], 1);
            stage[p] = (f[k] << 8) | tl[k];
        }
    }
    __syncthreads();

    // coalesced flush: wave per bucket (strided); lane-contiguous stores
    for (int b = wv; b < nbk; b += 16) {
        int ls = lofs[b];
        int le = hist[b];         // cursor == end of run
        int gd = gbase[b];
        for (int i = ls + lane; i < le; i += 64)
            be[gd + (i - ls)] = stage[i];
    }
}

// ---------------- pass 2: per-bucket hist + scan + scatter (bscan folded in) -----
// bstart[b] = sum_{k<b}(gcur[k]-k*CAP) computed by an in-block reduction over
// the (<=1024) bucket counters, removing the separate single-block scan kernel.
// Then per-bucket deg/dis/row_start + CSR scatter as before.

__global__ __launch_bounds__(1024) void k_scatter(const int* __restrict__ gcur,
                                                  const int* __restrict__ be,
                                                  int* __restrict__ row_start,
                                                  float* __restrict__ dis,
                                                  int* __restrict__ csr,
                                                  int N, int E) {
    __shared__ int hist[256];
    __shared__ int scn[256];
    __shared__ int wred[16];
    __shared__ int bstart_s;
    int b = blockIdx.x;
    int t = threadIdx.x;
    int lane = t & 63, wv = t >> 6;

    // block-wide reduction: sum of bucket counts for buckets k < b
    int v = (t < b) ? (gcur[t] - t * CAP) : 0;
    #pragma unroll
    for (int off = 32; off >= 1; off >>= 1) v += __shfl_xor(v, off);
    if (lane == 0) wred[wv] = v;
    if (t < 256) hist[t] = 0;
    __syncthreads();
    if (t == 0) {
        int s = 0;
        #pragma unroll
        for (int w = 0; w < 16; w++) s += wred[w];
        bstart_s = s;
        if (b == 0) row_start[N] = E;
    }

    int base = b * CAP;
    int cnt  = gcur[b] - base;
    for (int i = t; i < cnt; i += PTB)
        atomicAdd(&hist[be[base + i] & 255], 1);
    __syncthreads();

    int d = 0;
    if (t < 256) { d = hist[t]; scn[t] = d; }
    __syncthreads();
    #pragma unroll
    for (int off = 1; off < 256; off <<= 1) {
        int s2 = 0;
        if (t < 256) s2 = scn[t] + ((t >= off) ? scn[t - off] : 0);
        __syncthreads();
        if (t < 256) scn[t] = s2;
        __syncthreads();
    }
    if (t < 256) {
        int rs = bstart_s + (scn[t] - d);
        int node = (b << BSH) + t;
        if (node < N) {
            row_start[node] = rs;
            dis[node] = (d > 0) ? rsqrtf((float)d) : 0.0f;
        }
        hist[t] = rs;                               // becomes cursor
    }
    __syncthreads();

    for (int i = t; i < cnt; i += PTB) {
        int rec = be[base + i];
        int pos = atomicAdd(&hist[rec & 255], 1);
        csr[pos] = rec >> 8;
    }
}

// ---------------- emb0 = embedding + feature projection ----------------
// One wave handles NPW nodes; lane = dim. W column hoisted into registers once
// per wave. Feature loads are float4 broadcasts.
// out0 = fp32 emb0; y0 = bf16(dis * emb0) gather table.

__global__ __launch_bounds__(256) void k_emb0(const float* __restrict__ emb,
                       const float* __restrict__ uf,    // [NU,16]
                       const float* __restrict__ bn,    // [NB,8]
                       const float* __restrict__ bg,    // [NB,32]
                       const float* __restrict__ Wu,    // [16,64]
                       const float* __restrict__ bu,    // [64]
                       const float* __restrict__ Wn,    // [8,64]
                       const float* __restrict__ bnb,   // [64]
                       const float* __restrict__ Wg,    // [32,64]
                       const float* __restrict__ bgb,   // [64]
                       const float* __restrict__ dis,
                       float* __restrict__ out0, bf16* __restrict__ y0,
                       int N, int NU, int ublocks) {
    int lane = threadIdx.x & 63;
    int wsub = __builtin_amdgcn_readfirstlane(threadIdx.x >> 6);  // wave-uniform

    if (blockIdx.x < ublocks) {
        // ---- user nodes ----
        float w[16];
        #pragma unroll
        for (int k = 0; k < 16; k++) w[k] = Wu[k * D + lane];
        float bias = bu[lane];

        int node0 = (blockIdx.x * 4 + wsub) * NPW;
        for (int n = 0; n < NPW; n++) {
            int node = node0 + n;
            if (node >= NU) break;
            const float4* f = (const float4*)(uf + (size_t)node * 16);
            float4 f0 = f[0], f1 = f[1], f2 = f[2], f3 = f[3];
            float p = bias
                + f0.x * w[0]  + f0.y * w[1]  + f0.z * w[2]  + f0.w * w[3]
                + f1.x * w[4]  + f1.y * w[5]  + f1.z * w[6]  + f1.w * w[7]
                + f2.x * w[8]  + f2.y * w[9]  + f2.z * w[10] + f2.w * w[11]
                + f3.x * w[12] + f3.y * w[13] + f3.z * w[14] + f3.w * w[15];
            size_t idx = (size_t)node * D + lane;
            float v = emb[idx] + p;
            out0[idx] = v;
            y0[idx]   = __float2bfloat16(dis[node] * v);
        }
    } else {
        // ---- book nodes ----
        float wn[8], wg[32];
        #pragma unroll
        for (int k = 0; k < 8; k++)  wn[k] = Wn[k * D + lane];
        #pragma unroll
        for (int k = 0; k < 32; k++) wg[k] = Wg[k * D + lane];
        float bias = bnb[lane] + bgb[lane];

        int b0 = ((blockIdx.x - ublocks) * 4 + wsub) * NPW;
        for (int n = 0; n < NPW; n++) {
            int b = b0 + n;
            int node = NU + b;
            if (node >= N) break;
            const float4* fn = (const float4*)(bn + (size_t)b * 8);
            float4 n0 = fn[0], n1 = fn[1];
            const float4* fg = (const float4*)(bg + (size_t)b * 32);
            float p = bias
                + n0.x * wn[0] + n0.y * wn[1] + n0.z * wn[2] + n0.w * wn[3]
                + n1.x * wn[4] + n1.y * wn[5] + n1.z * wn[6] + n1.w * wn[7];
            #pragma unroll
            for (int q = 0; q < 8; q++) {
                float4 g = fg[q];
                p += g.x * wg[4*q]   + g.y * wg[4*q+1]
                   + g.z * wg[4*q+2] + g.w * wg[4*q+3];
            }
            size_t idx = (size_t)node * D + lane;
            float v = emb[idx] + p;
            out0[idx] = v;
            y0[idx]   = __float2bfloat16(dis[node] * v);
        }
    }
}

// ---------------- bf16x2 helpers ----------------

static __device__ __forceinline__ unsigned int pack_bf16x2(float e, float o) {
    bf16 a = __float2bfloat16(e);
    bf16 b = __float2bfloat16(o);
    unsigned short ua = __builtin_bit_cast(unsigned short, a);
    unsigned short ub = __builtin_bit_cast(unsigned short, b);
    return (unsigned int)ua | ((unsigned int)ub << 16);
}

// ---------------- gather core: GNP consecutive nodes per wave, interleaved -------
// Round-4 structure (best measured): 2 edges per dword load, lanes 0-31 even
// edges / 32-63 odd edges, csr coop-load + shfl distribute. Consecutive nodes
// keep row_start/csr reads streaming (round-6 lesson: randomizing them costs
// 2.3x). GNP csr + 8*GNP gather loads in flight per chunk iteration. Out-of-
// range slots clamp the address to the row's last edge and mask the value.

static __device__ __forceinline__ void gatherG(
        const int* __restrict__ row_start, const int* __restrict__ csr,
        const unsigned int* __restrict__ y32, int n0, int N, int lane,
        float (&a0)[GNP], float (&a1)[GNP]) {
    int half = lane >> 5;
    int lh   = lane & 31;
    int l16  = lane & 15;

    int sv[GNP], ev[GNP];
    #pragma unroll
    for (int g = 0; g < GNP; g++) {
        int node = min(n0 + g, N - 1);
        sv[g] = row_start[node];
        ev[g] = row_start[node + 1];
        a0[g] = 0.f;
        a1[g] = 0.f;
    }

    for (int c = 0; ; c++) {
        int jv[GNP], base[GNP];
        #pragma unroll
        for (int g = 0; g < GNP; g++) {
            base[g] = sv[g] + 16 * c;
            jv[g] = csr[min(base[g] + l16, max(ev[g] - 1, 0))];
        }
        #pragma unroll
        for (int u = 0; u < 8; u++) {
            #pragma unroll
            for (int g = 0; g < GNP; g++) {
                int idx = 2 * u + half;
                int j = __shfl(jv[g], idx);
                unsigned int d = y32[((unsigned int)j << 5) + lh];
                d = (base[g] + idx < ev[g]) ? d : 0u;
                a0[g] += __uint_as_float(d << 16);
                a1[g] += __uint_as_float(d & 0xffff0000u);
            }
        }
        bool cont = false;
        #pragma unroll
        for (int g = 0; g < GNP; g++) cont = cont || (base[g] + 16 < ev[g]);
        if (!cont) break;
    }

    // combine even-edge and odd-edge streams across halves
    #pragma unroll
    for (int g = 0; g < GNP; g++) {
        a0[g] += __shfl_xor(a0[g], 32);
        a1[g] += __shfl_xor(a1[g], 32);
    }
}

// ---------------- propagation layer ----------------
// y_in is pre-scaled by dis[src]. x = dis[t]*sum; y_out = bf16(dis[t]*x).
// Lane lh holds dims {2lh, 2lh+1}; half 0 stores x_out, half 1 stores y_out.

__global__ __launch_bounds__(256) void k_prop(const int* __restrict__ row_start,
                       const int* __restrict__ csr,
                       const float* __restrict__ dis,
                       const bf16* __restrict__ y_in,
                       bf16* __restrict__ x_out,
                       bf16* __restrict__ y_out, int N) {
    int lane = threadIdx.x & 63;
    int n0 = (blockIdx.x * 4 + (threadIdx.x >> 6)) * GNP;
    if (n0 >= N) return;

    float a0[GNP], a1[GNP];
    gatherG(row_start, csr, (const unsigned int*)y_in, n0, N, lane, a0, a1);

    int half = lane >> 5;
    int lh   = lane & 31;
    #pragma unroll
    for (int g = 0; g < GNP; g++) {
        int node = n0 + g;
        if (node >= N) break;
        float dt = dis[node];
        float x0  = dt * a0[g];
        float x1v = dt * a1[g];
        unsigned int w = (unsigned int)node * 32 + lh;
        if (half == 0) {
            ((unsigned int*)x_out)[w] = pack_bf16x2(x0, x1v);
        } else {
            ((unsigned int*)y_out)[w] = pack_bf16x2(dt * x0, dt * x1v);
        }
    }
}

// ---------------- last layer fused with final mean: out1 = (e0 + x1 + x2 + x3)/4 ----

__global__ __launch_bounds__(256) void k_prop_last(const int* __restrict__ row_start,
                       const int* __restrict__ csr,
                       const float* __restrict__ dis,
                       const bf16* __restrict__ y_in,
                       const float* __restrict__ out0,
                       const bf16* __restrict__ x1,
                       const bf16* __restrict__ x2,
                       float* __restrict__ out1, int N) {
    int lane = threadIdx.x & 63;
    int n0 = (blockIdx.x * 4 + (threadIdx.x >> 6)) * GNP;
    if (n0 >= N) return;

    float a0[GNP], a1[GNP];
    gatherG(row_start, csr, (const unsigned int*)y_in, n0, N, lane, a0, a1);

    int half = lane >> 5;
    int lh   = lane & 31;
    #pragma unroll
    for (int g = 0; g < GNP; g++) {
        int node = n0 + g;
        if (node >= N) break;
        float dt = dis[node];
        float x3e = dt * a0[g];   // even dim of pair
        float x3o = dt * a1[g];   // odd dim of pair
        if (half == 0) {
            unsigned int w = (unsigned int)node * 32 + lh;
            float2 o0 = ((const float2*)out0)[w];
            unsigned int p1 = ((const unsigned int*)x1)[w];
            unsigned int p2 = ((const unsigned int*)x2)[w];
            float e1 = __uint_as_float(p1 << 16);
            float o1 = __uint_as_float(p1 & 0xffff0000u);
            float e2 = __uint_as_float(p2 << 16);
            float o2 = __uint_as_float(p2 & 0xffff0000u);
            float2 r;
            r.x = (o0.x + e1 + e2 + x3e) * 0.25f;
            r.y = (o0.y + o1 + o2 + x3o) * 0.25f;
            ((float2*)out1)[w] = r;
        }
    }
}

// ---------------- launch ----------------

extern "C" void kernel_launch(void* const* d_in, const int* in_sizes, int n_in,
                              void* d_out, int out_size, void* d_ws, size_t ws_size,
                              hipStream_t stream) {
    const int E  = in_sizes[0] / 2;
    const int N  = in_sizes[1] / D;
    const int NU = in_sizes[2] / 16;
    const int nbk = (N + 255) >> BSH;        // buckets of 256 nodes (<= 1024 required)

    const int*   frm = (const int*)d_in[0];
    const int*   to  = frm + E;
    const float* emb = (const float*)d_in[1];
    const float* uf  = (const float*)d_in[2];
    const float* bn  = (const float*)d_in[3];
    const float* bg  = (const float*)d_in[4];
    const float* Wu  = (const float*)d_in[5];
    const float* bu  = (const float*)d_in[6];
    const float* Wn  = (const float*)d_in[7];
    const float* bnb = (const float*)d_in[8];
    const float* Wg  = (const float*)d_in[9];
    const float* bgb = (const float*)d_in[10];

    // workspace layout
    char* p = (char*)d_ws;
    const size_t ND = (size_t)N * D;
    bf16*  y0        = (bf16*)p;   p += ND * sizeof(bf16);    // also reused as y2
    bf16*  y1        = (bf16*)p;   p += ND * sizeof(bf16);
    bf16*  x1        = (bf16*)p;   p += ND * sizeof(bf16);
    bf16*  x2        = (bf16*)p;   p += ND * sizeof(bf16);
    float* dis       = (float*)p;  p += (size_t)N * sizeof(float);
    int*   row_start = (int*)p;    p += ((size_t)N + 16) * sizeof(int);
    int*   gcur      = (int*)p;    p += (size_t)nbk * sizeof(int);
    int*   csr       = (int*)p;    p += (size_t)E * sizeof(int);
    int*   be        = (int*)p;    p += (size_t)nbk * CAP * sizeof(int);

    const int TB = 256;
    const int gridProp = (N + 4 * GNP - 1) / (4 * GNP);  // GNP nodes/wave, 4 waves/block
    const int gridPart = (E + EPB - 1) / EPB;

    k_initcur<<<(nbk + TB - 1) / TB, TB, 0, stream>>>(gcur, nbk);
    k_part   <<<gridPart, PTB, 0, stream>>>(frm, to, gcur, be, E, nbk);
    k_scatter<<<nbk, PTB, 0, stream>>>(gcur, be, row_start, dis, csr, N, E);

    float* out0 = (float*)d_out;       // emb0 output (fp32)
    float* out1 = out0 + ND;           // layer-mean output (fp32)

    // k_emb0: one wave per NPW nodes; user blocks then book blocks in one launch
    const int NB = N - NU;
    const int uwaves  = (NU + NPW - 1) / NPW;
    const int ublocks = (uwaves + 3) / 4;
    const int bwaves  = (NB + NPW - 1) / NPW;
    const int bblocks = (bwaves + 3) / 4;
    k_emb0<<<ublocks + bblocks, TB, 0, stream>>>(emb, uf, bn, bg, Wu, bu, Wn, bnb,
                                                 Wg, bgb, dis, out0, y0, N, NU, ublocks);

    k_prop     <<<gridProp, TB, 0, stream>>>(row_start, csr, dis, y0, x1, y1, N);
    k_prop     <<<gridProp, TB, 0, stream>>>(row_start, csr, dis, y1, x2, y0, N);  // y2 -> y0
    k_prop_last<<<gridProp, TB, 0, stream>>>(row_start, csr, dis, y0, out0, x1, x2, out1, N);
}

// Round 9
// 376.920 us; speedup vs baseline: 1.3606x; 1.0349x over previous
//
#include <hip/hip_runtime.h>
#include <hip/hip_bf16.h>

typedef __hip_bfloat16 bf16;

#define D 64        // LATENT
#define BSH 8       // 256 nodes per bucket
#define CAP 5120    // bucket capacity (mean 4096, sigma ~64 -> 16 sigma margin)
#define EPB 16384   // edges per k_part block (LDS-staged)
#define PTB 1024    // k_part / k_scatter threads per block
#define NPW 8       // nodes per wave in k_emb0 (amortizes W-register loads)
#define GNP 4       // consecutive nodes per wave in prop kernels (R4 optimum; 6 regressed)

// ---------------- pass 1: partition edges into target buckets ----------------
// record = (frm << 8) | (to & 255); bucket = to >> 8, fixed CAP region per bucket.
// gcur[b] is a pure COUNT (memset-0 init); be position = b*CAP + count.
// LDS-staged counting sort: random scatter goes to LDS; global writes are
// coalesced per-bucket runs.

__global__ __launch_bounds__(1024) void k_part(const int* __restrict__ frm,
                                               const int* __restrict__ to,
                                               int* __restrict__ gcur,
                                               int* __restrict__ be, int E, int nbk) {
    __shared__ int hist[1024];    // bucket count, then running LDS cursor
    __shared__ int lofs[1024];    // exclusive scan (static)
    __shared__ int gbase[1024];   // reserved global base per bucket
    __shared__ int wsum[16];
    __shared__ int stage[EPB];    // staged records (64 KB)

    int tid = threadIdx.x;
    hist[tid] = 0;
    __syncthreads();

    int base = blockIdx.x * EPB;
    int  f[16], bk[16], tl[16];
    bool va[16];
    #pragma unroll
    for (int k = 0; k < 16; k++) {
        int i = base + k * PTB + tid;
        va[k] = (i < E);
        int ic = va[k] ? i : base;
        int t = to[ic];
        f[k]  = frm[ic];
        bk[k] = t >> BSH;
        tl[k] = t & 255;
        if (va[k]) atomicAdd(&hist[bk[k]], 1);
    }
    __syncthreads();

    // exclusive scan of hist (wave shfl scan + wave-sum scan)
    int c = hist[tid];
    int lane = tid & 63, wv = tid >> 6;
    int x = c;
    #pragma unroll
    for (int off = 1; off < 64; off <<= 1) {
        int y = __shfl_up(x, off);
        if (lane >= off) x += y;
    }
    if (lane == 63) wsum[wv] = x;
    __syncthreads();
    if (wv == 0) {
        int wval = (lane < 16) ? wsum[lane] : 0;
        #pragma unroll
        for (int off = 1; off < 16; off <<= 1) {
            int y = __shfl_up(wval, off);
            if (lane >= off) wval += y;
        }
        if (lane < 16) wsum[lane] = wval;
    }
    __syncthreads();
    int excl = x + (wv ? wsum[wv - 1] : 0) - c;
    lofs[tid]  = excl;
    gbase[tid] = (c > 0 && tid < nbk) ? (tid * CAP + atomicAdd(&gcur[tid], c)) : 0;
    hist[tid]  = excl;            // running cursor
    __syncthreads();

    // scatter records into LDS staging
    #pragma unroll
    for (int k = 0; k < 16; k++) {
        if (va[k]) {
            int p = atomicAdd(&hist[bk[k]], 1);
            stage[p] = (f[k] << 8) | tl[k];
        }
    }
    __syncthreads();

    // coalesced flush: wave per bucket (strided); lane-contiguous stores
    for (int b = wv; b < nbk; b += 16) {
        int ls = lofs[b];
        int le = hist[b];         // cursor == end of run
        int gd = gbase[b];
        for (int i = ls + lane; i < le; i += 64)
            be[gd + (i - ls)] = stage[i];
    }
}

// ---------------- pass 2: per-bucket hist + scan + scatter (bscan folded in) -----
// bstart[b] = sum_{k<b} gcur[k] via in-block reduction (gcur holds counts).
// Then per-bucket deg/dis/row_start + CSR scatter.

__global__ __launch_bounds__(1024) void k_scatter(const int* __restrict__ gcur,
                                                  const int* __restrict__ be,
                                                  int* __restrict__ row_start,
                                                  float* __restrict__ dis,
                                                  int* __restrict__ csr,
                                                  int N, int E) {
    __shared__ int hist[256];
    __shared__ int scn[256];
    __shared__ int wred[16];
    __shared__ int bstart_s;
    int b = blockIdx.x;
    int t = threadIdx.x;
    int lane = t & 63, wv = t >> 6;

    // block-wide reduction: sum of bucket counts for buckets k < b
    int v = (t < b) ? gcur[t] : 0;
    #pragma unroll
    for (int off = 32; off >= 1; off >>= 1) v += __shfl_xor(v, off);
    if (lane == 0) wred[wv] = v;
    if (t < 256) hist[t] = 0;
    __syncthreads();
    if (t == 0) {
        int s = 0;
        #pragma unroll
        for (int w = 0; w < 16; w++) s += wred[w];
        bstart_s = s;
        if (b == 0) row_start[N] = E;
    }

    int base = b * CAP;
    int cnt  = gcur[b];
    for (int i = t; i < cnt; i += PTB)
        atomicAdd(&hist[be[base + i] & 255], 1);
    __syncthreads();

    int d = 0;
    if (t < 256) { d = hist[t]; scn[t] = d; }
    __syncthreads();
    #pragma unroll
    for (int off = 1; off < 256; off <<= 1) {
        int s2 = 0;
        if (t < 256) s2 = scn[t] + ((t >= off) ? scn[t - off] : 0);
        __syncthreads();
        if (t < 256) scn[t] = s2;
        __syncthreads();
    }
    if (t < 256) {
        int rs = bstart_s + (scn[t] - d);
        int node = (b << BSH) + t;
        if (node < N) {
            row_start[node] = rs;
            dis[node] = (d > 0) ? rsqrtf((float)d) : 0.0f;
        }
        hist[t] = rs;                               // becomes cursor
    }
    __syncthreads();

    for (int i = t; i < cnt; i += PTB) {
        int rec = be[base + i];
        int pos = atomicAdd(&hist[rec & 255], 1);
        csr[pos] = rec >> 8;
    }
}

// ---------------- emb0 = embedding + feature projection ----------------
// One wave handles NPW nodes; lane = dim. W column hoisted into registers once
// per wave. Feature loads are float4 broadcasts.
// out0 = fp32 emb0; y0 = bf16(dis * emb0) gather table.

__global__ __launch_bounds__(256) void k_emb0(const float* __restrict__ emb,
                       const float* __restrict__ uf,    // [NU,16]
                       const float* __restrict__ bn,    // [NB,8]
                       const float* __restrict__ bg,    // [NB,32]
                       const float* __restrict__ Wu,    // [16,64]
                       const float* __restrict__ bu,    // [64]
                       const float* __restrict__ Wn,    // [8,64]
                       const float* __restrict__ bnb,   // [64]
                       const float* __restrict__ Wg,    // [32,64]
                       const float* __restrict__ bgb,   // [64]
                       const float* __restrict__ dis,
                       float* __restrict__ out0, bf16* __restrict__ y0,
                       int N, int NU, int ublocks) {
    int lane = threadIdx.x & 63;
    int wsub = __builtin_amdgcn_readfirstlane(threadIdx.x >> 6);  // wave-uniform

    if (blockIdx.x < ublocks) {
        // ---- user nodes ----
        float w[16];
        #pragma unroll
        for (int k = 0; k < 16; k++) w[k] = Wu[k * D + lane];
        float bias = bu[lane];

        int node0 = (blockIdx.x * 4 + wsub) * NPW;
        for (int n = 0; n < NPW; n++) {
            int node = node0 + n;
            if (node >= NU) break;
            const float4* f = (const float4*)(uf + (size_t)node * 16);
            float4 f0 = f[0], f1 = f[1], f2 = f[2], f3 = f[3];
            float p = bias
                + f0.x * w[0]  + f0.y * w[1]  + f0.z * w[2]  + f0.w * w[3]
                + f1.x * w[4]  + f1.y * w[5]  + f1.z * w[6]  + f1.w * w[7]
                + f2.x * w[8]  + f2.y * w[9]  + f2.z * w[10] + f2.w * w[11]
                + f3.x * w[12] + f3.y * w[13] + f3.z * w[14] + f3.w * w[15];
            size_t idx = (size_t)node * D + lane;
            float v = emb[idx] + p;
            out0[idx] = v;
            y0[idx]   = __float2bfloat16(dis[node] * v);
        }
    } else {
        // ---- book nodes ----
        float wn[8], wg[32];
        #pragma unroll
        for (int k = 0; k < 8; k++)  wn[k] = Wn[k * D + lane];
        #pragma unroll
        for (int k = 0; k < 32; k++) wg[k] = Wg[k * D + lane];
        float bias = bnb[lane] + bgb[lane];

        int b0 = ((blockIdx.x - ublocks) * 4 + wsub) * NPW;
        for (int n = 0; n < NPW; n++) {
            int b = b0 + n;
            int node = NU + b;
            if (node >= N) break;
            const float4* fn = (const float4*)(bn + (size_t)b * 8);
            float4 n0 = fn[0], n1 = fn[1];
            const float4* fg = (const float4*)(bg + (size_t)b * 32);
            float p = bias
                + n0.x * wn[0] + n0.y * wn[1] + n0.z * wn[2] + n0.w * wn[3]
                + n1.x * wn[4] + n1.y * wn[5] + n1.z * wn[6] + n1.w * wn[7];
            #pragma unroll
            for (int q = 0; q < 8; q++) {
                float4 g = fg[q];
                p += g.x * wg[4*q]   + g.y * wg[4*q+1]
                   + g.z * wg[4*q+2] + g.w * wg[4*q+3];
            }
            size_t idx = (size_t)node * D + lane;
            float v = emb[idx] + p;
            out0[idx] = v;
            y0[idx]   = __float2bfloat16(dis[node] * v);
        }
    }
}

// ---------------- bf16x2 helpers ----------------

static __device__ __forceinline__ unsigned int pack_bf16x2(float e, float o) {
    bf16 a = __float2bfloat16(e);
    bf16 b = __float2bfloat16(o);
    unsigned short ua = __builtin_bit_cast(unsigned short, a);
    unsigned short ub = __builtin_bit_cast(unsigned short, b);
    return (unsigned int)ua | ((unsigned int)ub << 16);
}

// ---------------- gather core: 4 consecutive nodes per wave, interleaved ---------
// R4 structure exactly (best measured: 65 us, 3.34 TB/s L2-fill): 2 edges per
// dword load, lanes 0-31 even edges / 32-63 odd edges, csr coop-load + shfl
// distribute. 4 csr + 32 gather loads in flight per chunk iteration. Consecutive
// nodes keep row_start/csr streaming (R6: randomizing costs 2.3x). GNP=6
// regressed (R8: occupancy 62->48%).

static __device__ __forceinline__ void gather4(
        const int* __restrict__ row_start, const int* __restrict__ csr,
        const unsigned int* __restrict__ y32, int n0, int N, int lane,
        float (&a0)[GNP], float (&a1)[GNP]) {
    int half = lane >> 5;
    int lh   = lane & 31;
    int l16  = lane & 15;

    int sv[GNP], ev[GNP];
    #pragma unroll
    for (int g = 0; g < GNP; g++) {
        int node = min(n0 + g, N - 1);
        sv[g] = row_start[node];
        ev[g] = row_start[node + 1];
        a0[g] = 0.f;
        a1[g] = 0.f;
    }

    for (int c = 0; ; c++) {
        int jv[GNP], base[GNP];
        #pragma unroll
        for (int g = 0; g < GNP; g++) {
            base[g] = sv[g] + 16 * c;
            jv[g] = csr[min(base[g] + l16, max(ev[g] - 1, 0))];
        }
        #pragma unroll
        for (int u = 0; u < 8; u++) {
            #pragma unroll
            for (int g = 0; g < GNP; g++) {
                int idx = 2 * u + half;
                int j = __shfl(jv[g], idx);
                unsigned int d = y32[((unsigned int)j << 5) + lh];
                d = (base[g] + idx < ev[g]) ? d : 0u;
                a0[g] += __uint_as_float(d << 16);
                a1[g] += __uint_as_float(d & 0xffff0000u);
            }
        }
        bool cont = false;
        #pragma unroll
        for (int g = 0; g < GNP; g++) cont = cont || (base[g] + 16 < ev[g]);
        if (!cont) break;
    }

    // combine even-edge and odd-edge streams across halves
    #pragma unroll
    for (int g = 0; g < GNP; g++) {
        a0[g] += __shfl_xor(a0[g], 32);
        a1[g] += __shfl_xor(a1[g], 32);
    }
}

// ---------------- propagation layer ----------------
// y_in is pre-scaled by dis[src]. x = dis[t]*sum; y_out = bf16(dis[t]*x).
// Lane lh holds dims {2lh, 2lh+1}; half 0 stores x_out, half 1 stores y_out.

__global__ __launch_bounds__(256) void k_prop(const int* __restrict__ row_start,
                       const int* __restrict__ csr,
                       const float* __restrict__ dis,
                       const bf16* __restrict__ y_in,
                       bf16* __restrict__ x_out,
                       bf16* __restrict__ y_out, int N) {
    int lane = threadIdx.x & 63;
    int n0 = (blockIdx.x * 4 + (threadIdx.x >> 6)) * GNP;
    if (n0 >= N) return;

    float a0[GNP], a1[GNP];
    gather4(row_start, csr, (const unsigned int*)y_in, n0, N, lane, a0, a1);

    int half = lane >> 5;
    int lh   = lane & 31;
    #pragma unroll
    for (int g = 0; g < GNP; g++) {
        int node = n0 + g;
        if (node >= N) break;
        float dt = dis[node];
        float x0  = dt * a0[g];
        float x1v = dt * a1[g];
        unsigned int w = (unsigned int)node * 32 + lh;
        if (half == 0) {
            ((unsigned int*)x_out)[w] = pack_bf16x2(x0, x1v);
        } else {
            ((unsigned int*)y_out)[w] = pack_bf16x2(dt * x0, dt * x1v);
        }
    }
}

// ---------------- last layer fused with final mean: out1 = (e0 + x1 + x2 + x3)/4 ----

__global__ __launch_bounds__(256) void k_prop_last(const int* __restrict__ row_start,
                       const int* __restrict__ csr,
                       const float* __restrict__ dis,
                       const bf16* __restrict__ y_in,
                       const float* __restrict__ out0,
                       const bf16* __restrict__ x1,
                       const bf16* __restrict__ x2,
                       float* __restrict__ out1, int N) {
    int lane = threadIdx.x & 63;
    int n0 = (blockIdx.x * 4 + (threadIdx.x >> 6)) * GNP;
    if (n0 >= N) return;

    float a0[GNP], a1[GNP];
    gather4(row_start, csr, (const unsigned int*)y_in, n0, N, lane, a0, a1);

    int half = lane >> 5;
    int lh   = lane & 31;
    #pragma unroll
    for (int g = 0; g < GNP; g++) {
        int node = n0 + g;
        if (node >= N) break;
        float dt = dis[node];
        float x3e = dt * a0[g];   // even dim of pair
        float x3o = dt * a1[g];   // odd dim of pair
        if (half == 0) {
            unsigned int w = (unsigned int)node * 32 + lh;
            float2 o0 = ((const float2*)out0)[w];
            unsigned int p1 = ((const unsigned int*)x1)[w];
            unsigned int p2 = ((const unsigned int*)x2)[w];
            float e1 = __uint_as_float(p1 << 16);
            float o1 = __uint_as_float(p1 & 0xffff0000u);
            float e2 = __uint_as_float(p2 << 16);
            float o2 = __uint_as_float(p2 & 0xffff0000u);
            float2 r;
            r.x = (o0.x + e1 + e2 + x3e) * 0.25f;
            r.y = (o0.y + o1 + o2 + x3o) * 0.25f;
            ((float2*)out1)[w] = r;
        }
    }
}

// ---------------- launch ----------------

extern "C" void kernel_launch(void* const* d_in, const int* in_sizes, int n_in,
                              void* d_out, int out_size, void* d_ws, size_t ws_size,
                              hipStream_t stream) {
    const int E  = in_sizes[0] / 2;
    const int N  = in_sizes[1] / D;
    const int NU = in_sizes[2] / 16;
    const int nbk = (N + 255) >> BSH;        // buckets of 256 nodes (<= 1024 required)

    const int*   frm = (const int*)d_in[0];
    const int*   to  = frm + E;
    const float* emb = (const float*)d_in[1];
    const float* uf  = (const float*)d_in[2];
    const float* bn  = (const float*)d_in[3];
    const float* bg  = (const float*)d_in[4];
    const float* Wu  = (const float*)d_in[5];
    const float* bu  = (const float*)d_in[6];
    const float* Wn  = (const float*)d_in[7];
    const float* bnb = (const float*)d_in[8];
    const float* Wg  = (const float*)d_in[9];
    const float* bgb = (const float*)d_in[10];

    // workspace layout
    char* p = (char*)d_ws;
    const size_t ND = (size_t)N * D;
    bf16*  y0        = (bf16*)p;   p += ND * sizeof(bf16);    // also reused as y2
    bf16*  y1        = (bf16*)p;   p += ND * sizeof(bf16);
    bf16*  x1        = (bf16*)p;   p += ND * sizeof(bf16);
    bf16*  x2        = (bf16*)p;   p += ND * sizeof(bf16);
    float* dis       = (float*)p;  p += (size_t)N * sizeof(float);
    int*   row_start = (int*)p;    p += ((size_t)N + 16) * sizeof(int);
    int*   gcur      = (int*)p;    p += (size_t)nbk * sizeof(int);
    int*   csr       = (int*)p;    p += (size_t)E * sizeof(int);
    int*   be        = (int*)p;    p += (size_t)nbk * CAP * sizeof(int);

    const int TB = 256;
    const int gridProp = (N + 4 * GNP - 1) / (4 * GNP);  // GNP nodes/wave, 4 waves/block
    const int gridPart = (E + EPB - 1) / EPB;

    hipMemsetAsync(gcur, 0, (size_t)nbk * sizeof(int), stream);  // gcur = counts
    k_part   <<<gridPart, PTB, 0, stream>>>(frm, to, gcur, be, E, nbk);
    k_scatter<<<nbk, PTB, 0, stream>>>(gcur, be, row_start, dis, csr, N, E);

    float* out0 = (float*)d_out;       // emb0 output (fp32)
    float* out1 = out0 + ND;           // layer-mean output (fp32)

    // k_emb0: one wave per NPW nodes; user blocks then book blocks in one launch
    const int NB = N - NU;
    const int uwaves  = (NU + NPW - 1) / NPW;
    const int ublocks = (uwaves + 3) / 4;
    const int bwaves  = (NB + NPW - 1) / NPW;
    const int bblocks = (bwaves + 3) / 4;
    k_emb0<<<ublocks + bblocks, TB, 0, stream>>>(emb, uf, bn, bg, Wu, bu, Wn, bnb,
                                                 Wg, bgb, dis, out0, y0, N, NU, ublocks);

    k_prop     <<<gridProp, TB, 0, stream>>>(row_start, csr, dis, y0, x1, y1, N);
    k_prop     <<<gridProp, TB, 0, stream>>>(row_start, csr, dis, y1, x2, y0, N);  // y2 -> y0
    k_prop_last<<<gridProp, TB, 0, stream>>>(row_start, csr, dis, y0, out0, x1, x2, out1, N);
}